// Round 1
// baseline (11386.610 us; speedup 1.0000x reference)
//
#include <hip/hip_runtime.h>
#include <math.h>

#define B_  16
#define TE_ 400
#define TD_ 64
#define E_  256
#define H_  512
#define H2_ 1024
#define V_  32000
#define KE_ 768     // E + H   (encoder matvec K)
#define KD_ 3328    // E + 2*H2 + H2 (decoder matvec K)

typedef __attribute__((ext_vector_type(4))) float f32x4;
typedef __attribute__((ext_vector_type(8))) short s16x8;
typedef __attribute__((ext_vector_type(8))) unsigned short u16x8;
typedef __attribute__((ext_vector_type(4))) unsigned short u16x4;

__device__ __forceinline__ float bf2f(unsigned short u){
  union { unsigned int i; float f; } v; v.i = ((unsigned int)u) << 16; return v.f;
}
__device__ __forceinline__ unsigned short f2bf(float f){
  union { float f; unsigned int i; } v; v.f = f;
  return (unsigned short)((v.i + 0x7fffu + ((v.i >> 16) & 1u)) >> 16);
}
__device__ __forceinline__ float sigmoidf_(float x){ return 1.f/(1.f + expf(-x)); }

__device__ __forceinline__ void gl_lds16(const void* gsrc, void* ldst){
  __builtin_amdgcn_global_load_lds(
      (const __attribute__((address_space(1))) unsigned int*)gsrc,
      (__attribute__((address_space(3))) unsigned int*)ldst, 16, 0, 0);
}

// device-scope grid barrier (all WGs co-resident by construction)
__device__ __forceinline__ void grid_bar(unsigned* cnt, unsigned* gen, unsigned nwg){
  __syncthreads();
  if (threadIdx.x == 0){
    __threadfence();
    unsigned g = __hip_atomic_load(gen, __ATOMIC_RELAXED, __HIP_MEMORY_SCOPE_AGENT);
    unsigned a = __hip_atomic_fetch_add(cnt, 1u, __ATOMIC_RELAXED, __HIP_MEMORY_SCOPE_AGENT);
    if (a == nwg - 1u){
      __hip_atomic_store(cnt, 0u, __ATOMIC_RELAXED, __HIP_MEMORY_SCOPE_AGENT);
      __hip_atomic_fetch_add(gen, 1u, __ATOMIC_RELEASE, __HIP_MEMORY_SCOPE_AGENT);
    } else {
      while (__hip_atomic_load(gen, __ATOMIC_RELAXED, __HIP_MEMORY_SCOPE_AGENT) == g)
        __builtin_amdgcn_s_sleep(2);
    }
    __threadfence();
  }
  __syncthreads();
}

// ---------------- init ----------------
__global__ void k_init(unsigned* bars, float* accum){
  int gid = blockIdx.x*256 + threadIdx.x;
  if (blockIdx.x == 0 && threadIdx.x < 16) bars[threadIdx.x] = 0u;
  if (gid < B_*TE_) accum[gid] = 0.f;
}

// ---------------- embedding gather (f32 -> bf16), out[(t*16+b)][e] ----------------
__global__ void k_gather(const float* __restrict__ emb, const int* __restrict__ idx,
                         unsigned short* __restrict__ out, int T){
  int wv = threadIdx.x >> 6, l = threadIdx.x & 63;
  int row = blockIdx.x*4 + wv;
  if (row >= T*B_) return;
  int t = row >> 4, b = row & 15;
  int tok = idx[b*T + t];
  float4 v = *(const float4*)(emb + (size_t)tok*E_ + l*4);
  u16x4 o; o[0]=f2bf(v.x); o[1]=f2bf(v.y); o[2]=f2bf(v.z); o[3]=f2bf(v.w);
  *(u16x4*)(out + (size_t)row*E_ + l*4) = o;
}

// ---------------- transpose+convert W_ea/W_da -> [j][d] bf16 ----------------
__global__ void k_transpose_bf(const float* __restrict__ src0, const float* __restrict__ src1,
                               unsigned short* __restrict__ dst0, unsigned short* __restrict__ dst1){
  const float* s = blockIdx.z ? src1 : src0;
  unsigned short* d = blockIdx.z ? dst1 : dst0;
  __shared__ float tile[32][33];
  int tx = threadIdx.x & 31, ty = threadIdx.x >> 5;
  int d0 = blockIdx.x*32, j0 = blockIdx.y*32;
  for (int yy = 0; yy < 32; yy += 8)
    tile[ty+yy][tx] = s[(size_t)(d0+ty+yy)*H2_ + j0 + tx];
  __syncthreads();
  for (int yy = 0; yy < 32; yy += 8)
    d[(size_t)(j0+ty+yy)*H2_ + d0 + tx] = f2bf(tile[tx][ty+yy]);
}

// ---------------- prep encoder weights: gate-grouped [dir][2048][768] bf16 ----------------
__global__ void k_prep_enc(const float* __restrict__ Wih_f, const float* __restrict__ Whh_f,
                           const float* __restrict__ Wih_b, const float* __restrict__ Whh_b,
                           unsigned short* __restrict__ Wenc){
  int it = blockIdx.x*256 + threadIdx.x;       // ushort8 chunks; total 2*2048*96
  int dir = it / (2048*96); int rem = it % (2048*96);
  int pr = rem / 96; int kc = rem % 96; int k0 = kc*8;
  int g = pr >> 6, r = pr & 63, gate = r >> 4, ul = r & 15;
  int orig = gate*H_ + g*16 + ul;
  const float* Wih = dir ? Wih_b : Wih_f;
  const float* Whh = dir ? Whh_b : Whh_f;
  u16x8 o;
  #pragma unroll
  for (int e = 0; e < 8; ++e){
    int k = k0 + e;
    float v = (k < E_) ? Wih[(size_t)orig*E_ + k] : Whh[(size_t)orig*H_ + (k - E_)];
    o[e] = f2bf(v);
  }
  *(u16x8*)(Wenc + ((size_t)dir*2048 + pr)*KE_ + k0) = o;
}

// ---------------- prep decoder weights: gate-grouped + XOR-swizzled blocks ----------------
// layout: g-block (64) of 425984B; kblk (26) x 16KB; row (64) x 256B; 16B chunk k8 XOR'd
__global__ void k_prep_dec(const float* __restrict__ Wih_d, const float* __restrict__ Whh_d,
                           unsigned short* __restrict__ Wd){
  int it = blockIdx.x*256 + threadIdx.x;       // total 64*26*64*16 = 1,703,936
  int g = it / (26*64*16); int rem = it % (26*64*16);
  int kblk = rem / (64*16); int rem2 = rem % (64*16);
  int row = rem2 >> 4; int k8 = rem2 & 15;
  int gate = row >> 4, ul = row & 15;
  int orig = gate*H2_ + g*16 + ul;
  int kbase = kblk*128 + k8*8;
  u16x8 o;
  #pragma unroll
  for (int e = 0; e < 8; ++e){
    int k = kbase + e;
    float v = (k < 2304) ? Wih_d[(size_t)orig*2304 + k] : Whh_d[(size_t)orig*H2_ + (k-2304)];
    o[e] = f2bf(v);
  }
  size_t byteoff = (size_t)g*425984 + (size_t)kblk*16384 + (size_t)(row*256 + ((k8*16) ^ ((row&7)<<4)));
  *(u16x8*)((char*)Wd + byteoff) = o;
}

// ---------------- persistent bi-LSTM encoder ----------------
__global__ void __launch_bounds__(256, 1) k_encoder(
    const unsigned short* __restrict__ xs,    // [6400][256]
    const unsigned short* __restrict__ Wenc,  // [2][2048][768]
    const float* __restrict__ b_f, const float* __restrict__ b_b,
    const float* __restrict__ h0, const float* __restrict__ c0,   // [2][16][512]
    unsigned short* __restrict__ enc_out,     // [16][400][1024]
    unsigned short* __restrict__ hbuf,        // [2][2][16][512]
    float* __restrict__ h0dec, float* __restrict__ c0dec,         // [16][1024]
    unsigned* __restrict__ bars)
{
  extern __shared__ char smem[];
  unsigned short* Wt = (unsigned short*)smem;            // [64][776]
  unsigned short* At = Wt + 64*776;                      // [16][776]
  float* zl = (float*)(At + 16*776);                     // [4][16][16]
  int tid = threadIdx.x;
  int w = blockIdx.x;
  int dir = w >> 5, g = w & 31;
  int wv = tid >> 6, l = tid & 63;
  // load Wt once
  {
    const unsigned short* Wsrc = Wenc + ((size_t)dir*2048 + g*64)*KE_;
    int r = tid >> 2, s = tid & 3;
    for (int c = 0; c < 24; ++c)
      *(u16x8*)(Wt + r*776 + s*192 + c*8) = *(const u16x8*)(Wsrc + (size_t)r*KE_ + s*192 + c*8);
  }
  const float* bias = dir ? b_b : b_f;
  int bb = tid >> 4, ul = tid & 15;
  float creg = c0[((size_t)dir*16 + bb)*H_ + g*16 + ul];
  int kchunk = (l >> 4) * 8;
  float bia = bias[wv*H_ + g*16 + (l&15)];
  f32x4 bias4 = { bia, bia, bia, bia };
  __syncthreads();
  for (int t = 0; t < TE_; ++t){
    int tg = dir ? (TE_-1 - t) : t;
    {
      int r = tid >> 4, s = tid & 15;
      *(u16x8*)(At + r*776 + s*16)     = *(const u16x8*)(xs + ((size_t)tg*16 + r)*E_ + s*16);
      *(u16x8*)(At + r*776 + s*16 + 8) = *(const u16x8*)(xs + ((size_t)tg*16 + r)*E_ + s*16 + 8);
      if (t == 0){
        for (int e = 0; e < 32; ++e)
          At[r*776 + 256 + s*32 + e] = f2bf(h0[((size_t)dir*16 + r)*H_ + s*32 + e]);
      } else {
        const unsigned short* hsrc = hbuf + ((size_t)dir*2 + (t&1))*(16*H_) + r*H_ + s*32;
        for (int c = 0; c < 4; ++c)
          *(u16x8*)(At + r*776 + 256 + s*32 + c*8) = *(const u16x8*)(hsrc + c*8);
      }
    }
    __syncthreads();
    f32x4 acc = bias4;
    const unsigned short* brow = Wt + (wv*16 + (l&15))*776 + kchunk;
    const unsigned short* ap   = At + (l&15)*776 + kchunk;
    #pragma unroll
    for (int ks = 0; ks < 24; ++ks){
      s16x8 afr = *(const s16x8*)(ap + ks*32);
      s16x8 bfr = *(const s16x8*)(brow + ks*32);
      acc = __builtin_amdgcn_mfma_f32_16x16x32_bf16(afr, bfr, acc, 0, 0, 0);
    }
    #pragma unroll
    for (int j = 0; j < 4; ++j)
      zl[wv*256 + ((l>>4)*4 + j)*16 + (l&15)] = acc[j];
    __syncthreads();
    float zi = zl[0*256 + bb*16 + ul];
    float zf = zl[1*256 + bb*16 + ul];
    float zg = zl[2*256 + bb*16 + ul];
    float zo = zl[3*256 + bb*16 + ul];
    float iv = sigmoidf_(zi), fv = sigmoidf_(zf), gv = tanhf(zg), ov = sigmoidf_(zo);
    float cc = fv*creg + iv*gv;
    float hh = ov * tanhf(cc);
    creg = cc;
    int u = g*16 + ul;
    unsigned short hb = f2bf(hh);
    hbuf[((size_t)dir*2 + ((t+1)&1))*(16*H_) + bb*H_ + u] = hb;
    enc_out[((size_t)bb*TE_ + tg)*H2_ + dir*H_ + u] = hb;
    if (t == TE_-1){
      h0dec[(size_t)bb*H2_ + dir*H_ + u] = hh;
      c0dec[(size_t)bb*H2_ + dir*H_ + u] = cc;
    }
    grid_bar(bars+0, bars+1, 64);
  }
}

__global__ void k_dec_init(const float* __restrict__ h0dec, unsigned short* __restrict__ hreg){
  int gid = blockIdx.x*256 + threadIdx.x;
  if (gid < 16384) hreg[gid] = f2bf(h0dec[gid]);
}

// ---------------- persistent attention decoder ----------------
__global__ void __launch_bounds__(256, 1) k_decoder(
  const unsigned short* __restrict__ dec_emb,  // [1024][256]
  const unsigned short* __restrict__ Wd,       // swizzled gate-grouped
  const float* __restrict__ b_d,
  const unsigned short* __restrict__ WeaT, const unsigned short* __restrict__ WdaT,
  const unsigned short* __restrict__ enc_out,  // [16][400][1024]
  const float* __restrict__ c0dec,
  unsigned short* __restrict__ hreg,    // [2][16][1024]
  unsigned short* __restrict__ xbuf,    // [16][2304]
  float* __restrict__ q,                // [2][16][1024]
  float* __restrict__ accum,            // [16][400]
  float* __restrict__ pctx,             // [128][1024]
  float* __restrict__ psum,             // [128]
  float* __restrict__ ctxd,             // [16][1024]
  float* __restrict__ bufh,             // [64][16][1024]
  unsigned short* __restrict__ Av,      // [1024][3072]
  float* __restrict__ outHC,            // [2][16][1024]
  unsigned* __restrict__ bars)
{
  extern __shared__ char smem[];
  int tid = threadIdx.x, w = blockIdx.x;
  int wv = tid >> 6, l = tid & 63;
  bool isL = (w < 64);
  int eb = 0, ec = 0;
  if (w >= 64){ eb = (w-64) >> 3; ec = (w-64) & 7; }

  unsigned short* encL = (unsigned short*)smem;          // [50][1024] (w>=64)
  float* qL  = (float*)(smem + 102400);
  float* epL = (float*)(smem + 106496);

  unsigned short* At = (unsigned short*)smem;            // [16][3336] (w<64, S4)
  char*  Bb = smem + 106752;                             // 16KB
  float* zl = (float*)(smem + 106752 + 16384);           // [4][16][16]

  unsigned short* Ah = (unsigned short*)smem;            // [16][1032] (S1)
  unsigned short* Wq = Ah + 16*1032;
  float* zq = (float*)(Wq + 16*1032);

  float* qL2  = (float*)smem;                            // (w<16, S2)
  float* dscL = (float*)(smem + 4096);

  if (w >= 64){
    for (int r = 0; r < 50; ++r){
      const unsigned short* src = enc_out + ((size_t)eb*TE_ + ec*50 + r)*H2_;
      *(u16x4*)(encL + r*1024 + tid*4) = *(const u16x4*)(src + tid*4);
    }
  }
  float creg = 0.f;
  int bb = tid >> 4, ul = tid & 15;

  for (int i = 0; i < TD_; ++i){
    // ---- S1: q_e = h@W_ea, q_d = h@W_da (WGs 0..63, 2 tile-tasks each) ----
    if (isL){
      int r = tid >> 4, s = tid & 15;
      const unsigned short* hsrc = hreg + (i&1)*16384 + r*H2_ + s*64;
      for (int c = 0; c < 8; ++c)
        *(u16x8*)(Ah + r*1032 + s*64 + c*8) = *(const u16x8*)(hsrc + c*8);
      __syncthreads();
      for (int task = 0; task < 2; ++task){
        int tt = w*2 + task;
        int kind = tt >> 6, jt = tt & 63;
        const unsigned short* Wsrc = (kind ? WdaT : WeaT) + (size_t)jt*16*H2_;
        for (int c = 0; c < 8; ++c)
          *(u16x8*)(Wq + r*1032 + s*64 + c*8) = *(const u16x8*)(Wsrc + (size_t)r*H2_ + s*64 + c*8);
        __syncthreads();
        f32x4 acc = {0.f,0.f,0.f,0.f};
        const unsigned short* ap = Ah + (l&15)*1032 + wv*256 + (l>>4)*8;
        const unsigned short* bp = Wq + (l&15)*1032 + wv*256 + (l>>4)*8;
        #pragma unroll
        for (int ks = 0; ks < 8; ++ks){
          s16x8 afr = *(const s16x8*)(ap + ks*32);
          s16x8 bfr = *(const s16x8*)(bp + ks*32);
          acc = __builtin_amdgcn_mfma_f32_16x16x32_bf16(afr, bfr, acc, 0,0,0);
        }
        #pragma unroll
        for (int j = 0; j < 4; ++j)
          zq[wv*256 + (l&15)*16 + (l>>4)*4 + j] = acc[j];
        __syncthreads();
        float qv = zq[0*256 + (tid&15)*16 + (tid>>4)] + zq[1*256 + (tid&15)*16 + (tid>>4)]
                 + zq[2*256 + (tid&15)*16 + (tid>>4)] + zq[3*256 + (tid&15)*16 + (tid>>4)];
        q[(size_t)kind*16384 + (size_t)(tid>>4)*H2_ + jt*16 + (tid&15)] = qv;
        __syncthreads();
      }
    }
    grid_bar(bars+2, bars+3, 192);

    // ---- S2: attention scores/partials ----
    if (w >= 64){
      int b = eb;
      for (int c = tid; c < 1024; c += 256) qL[c] = q[(size_t)b*H2_ + c];
      __syncthreads();
      for (int r = wv; r < 50; r += 4){
        const unsigned short* er = encL + r*1024 + l*16;
        u16x8 e0 = *(const u16x8*)(er);
        u16x8 e1 = *(const u16x8*)(er + 8);
        const float* qp = qL + l*16;
        float s = 0.f;
        #pragma unroll
        for (int c = 0; c < 8; ++c) s += qp[c]*bf2f(e0[c]);
        #pragma unroll
        for (int c = 0; c < 8; ++c) s += qp[8+c]*bf2f(e1[c]);
        #pragma unroll
        for (int o = 1; o < 64; o <<= 1) s += __shfl_xor(s, o);
        if (l == 0){
          int t = ec*50 + r;
          float es = expf(s);
          float aold = accum[b*TE_ + t];
          float denom = (i == 0) ? 1.f : aold;
          accum[b*TE_ + t] = aold + es;
          epL[r] = es / denom;
        }
      }
      __syncthreads();
      float tot = 0.f;
      for (int r = 0; r < 50; ++r) tot += epL[r];
      float a0=0.f,a1=0.f,a2=0.f,a3=0.f;
      for (int r = 0; r < 50; ++r){
        float wgt = epL[r];
        u16x4 ev = *(const u16x4*)(encL + r*1024 + tid*4);
        a0 += wgt*bf2f(ev[0]); a1 += wgt*bf2f(ev[1]); a2 += wgt*bf2f(ev[2]); a3 += wgt*bf2f(ev[3]);
      }
      int slot = w - 64;
      float4 o4; o4.x=a0; o4.y=a1; o4.z=a2; o4.w=a3;
      *(float4*)(pctx + (size_t)slot*1024 + tid*4) = o4;
      if (tid == 0) psum[slot] = tot;
    } else if (w < 16){
      int b = w;
      if (i == 0){
        for (int c = tid; c < 1024; c += 256) ctxd[(size_t)b*H2_ + c] = 0.f;
      } else {
        for (int c = tid; c < 1024; c += 256) qL2[c] = q[16384 + (size_t)b*H2_ + c];
        __syncthreads();
        for (int tp = wv; tp < i; tp += 4){
          const float* br = bufh + ((size_t)tp*16 + b)*H2_ + l*16;
          const float* qp = qL2 + l*16;
          float s = 0.f;
          #pragma unroll
          for (int c = 0; c < 16; ++c) s += qp[c]*br[c];
          #pragma unroll
          for (int o = 1; o < 64; o <<= 1) s += __shfl_xor(s, o);
          if (l == 0) dscL[tp] = s;
        }
        __syncthreads();
        float m = -1e30f;
        for (int tp = 0; tp < i; ++tp) m = fmaxf(m, dscL[tp]);
        float ssum = 0.f;
        for (int tp = 0; tp < i; ++tp) ssum += expf(dscL[tp]-m);
        float inv = 1.f/ssum;
        float c0_=0.f,c1_=0.f,c2_=0.f,c3_=0.f;
        for (int tp = 0; tp < i; ++tp){
          float wgt = expf(dscL[tp]-m)*inv;
          const float* br = bufh + ((size_t)tp*16 + b)*H2_ + tid*4;
          c0_ += wgt*br[0]; c1_ += wgt*br[1]; c2_ += wgt*br[2]; c3_ += wgt*br[3];
        }
        float4 o4; o4.x=c0_; o4.y=c1_; o4.z=c2_; o4.w=c3_;
        *(float4*)(ctxd + (size_t)b*H2_ + tid*4) = o4;
      }
    }
    grid_bar(bars+2, bars+3, 192);

    // ---- S3: finalize ctx, pack bf16 inputs ----
    if (w < 16){
      int b = w;
      float sx=0.f, sy=0.f, sz=0.f, sw=0.f, pst=0.f;
      for (int c = 0; c < 8; ++c){
        float4 v = *(const float4*)(pctx + (size_t)(b*8+c)*1024 + tid*4);
        sx += v.x; sy += v.y; sz += v.z; sw += v.w;
        pst += psum[b*8+c];
      }
      float inv = 1.f/pst;
      u16x4 o; o[0]=f2bf(sx*inv); o[1]=f2bf(sy*inv); o[2]=f2bf(sz*inv); o[3]=f2bf(sw*inv);
      *(u16x4*)(xbuf + (size_t)b*2304 + 256 + tid*4) = o;
      *(u16x4*)(Av + ((size_t)b*TD_ + i)*3072 + 1024 + tid*4) = o;
    } else if (w < 32){
      int b = w - 16;
      float4 v = *(const float4*)(ctxd + (size_t)b*H2_ + tid*4);
      u16x4 o; o[0]=f2bf(v.x); o[1]=f2bf(v.y); o[2]=f2bf(v.z); o[3]=f2bf(v.w);
      *(u16x4*)(xbuf + (size_t)b*2304 + 1280 + tid*4) = o;
      *(u16x4*)(Av + ((size_t)b*TD_ + i)*3072 + 2048 + tid*4) = o;
      if (tid < 32)
        *(u16x8*)(xbuf + (size_t)b*2304 + tid*8) = *(const u16x8*)(dec_emb + ((size_t)i*16 + b)*E_ + tid*8);
    }
    grid_bar(bars+2, bars+3, 192);

    // ---- S4: decoder LSTM matvec (WGs 0..63) ----
    if (isL){
      int r = tid >> 4, s = tid & 15;
      for (int c = 0; c < 18; ++c)
        *(u16x8*)(At + r*3336 + s*144 + c*8) = *(const u16x8*)(xbuf + (size_t)r*2304 + s*144 + c*8);
      for (int c = 0; c < 8; ++c)
        *(u16x8*)(At + r*3336 + 2304 + s*64 + c*8) = *(const u16x8*)(hreg + (i&1)*16384 + (size_t)r*H2_ + s*64 + c*8);
      __syncthreads();
      float bia = b_d[wv*H2_ + w*16 + (l&15)];
      f32x4 acc = { bia, bia, bia, bia };
      const char* gblk = (const char*)Wd + (size_t)w*425984;
      int r2 = wv*16 + (l&15);
      for (int kblk = 0; kblk < 26; ++kblk){
        const char* gsrc = gblk + (size_t)kblk*16384 + wv*4096;
        char* lbase = Bb + wv*4096;
        #pragma unroll
        for (int qq = 0; qq < 4; ++qq)
          gl_lds16(gsrc + qq*1024 + l*16, lbase + qq*1024);
        __syncthreads();
        const unsigned short* ap = At + (l&15)*3336 + kblk*128 + (l>>4)*8;
        #pragma unroll
        for (int ks = 0; ks < 4; ++ks){
          int k8 = ks*4 + (l>>4);
          int bby = r2*256 + ((k8*16) ^ ((r2&7)<<4));
          s16x8 afr = *(const s16x8*)(ap + ks*32);
          s16x8 bfr = *(const s16x8*)(Bb + bby);
          acc = __builtin_amdgcn_mfma_f32_16x16x32_bf16(afr, bfr, acc, 0,0,0);
        }
        __syncthreads();
      }
      #pragma unroll
      for (int j = 0; j < 4; ++j)
        zl[wv*256 + ((l>>4)*4+j)*16 + (l&15)] = acc[j];
      __syncthreads();
      float zi = zl[0*256 + bb*16 + ul];
      float zf = zl[1*256 + bb*16 + ul];
      float zg = zl[2*256 + bb*16 + ul];
      float zo = zl[3*256 + bb*16 + ul];
      if (i == 0) creg = c0dec[(size_t)bb*H2_ + w*16 + ul];
      float iv = sigmoidf_(zi), fv = sigmoidf_(zf), gv = tanhf(zg), ov = sigmoidf_(zo);
      float cc = fv*creg + iv*gv;
      float hh = ov*tanhf(cc);
      creg = cc;
      int u = w*16 + ul;
      hreg[((i+1)&1)*16384 + (size_t)bb*H2_ + u] = f2bf(hh);
      Av[((size_t)bb*TD_ + i)*3072 + u] = f2bf(hh);
      bufh[((size_t)i*16 + bb)*H2_ + u] = hh;
      if (i == TD_-1){
        outHC[(size_t)bb*H2_ + u] = hh;
        outHC[16384 + (size_t)bb*H2_ + u] = cc;
      }
    }
    grid_bar(bars+2, bars+3, 192);
  }
}

// ---------------- vocab GEMM: C = Av(bf16) @ Wv(f32->bf16)^T + b_v ----------------
__global__ void __launch_bounds__(256, 2) k_vocab_gemm(
    const unsigned short* __restrict__ Av,   // [1024][3072]
    const float* __restrict__ Wv,            // [32000][3072]
    const float* __restrict__ bv,
    float* __restrict__ out)                 // [1024][32000]
{
  __shared__ unsigned short Ab[128*72];
  __shared__ unsigned short Bt[128*72];
  int p = blockIdx.x;
  int mt = (p>>3)&7, nt = (p&7) + 8*(p>>6);
  if (nt >= 250) return;
  int m0 = mt*128, n0 = nt*128;
  int tid = threadIdx.x, wvv = tid>>6, l = tid&63;
  int wr = wvv>>1, wc = wvv&1;
  f32x4 zero4 = {0.f,0.f,0.f,0.f};
  f32x4 acc[4][4];
  #pragma unroll
  for (int a=0;a<4;++a){
    #pragma unroll
    for (int b=0;b<4;++b) acc[a][b] = zero4;
  }
  for (int k0 = 0; k0 < 3072; k0 += 64){
    #pragma unroll
    for (int qq = 0; qq < 4; ++qq){
      int idx8 = (tid + qq*256)*8;
      int r = idx8 >> 6, k = idx8 & 63;
      *(u16x8*)(Ab + r*72 + k) = *(const u16x8*)(Av + (size_t)(m0+r)*3072 + k0 + k);
    }
    #pragma unroll
    for (int qq = 0; qq < 4; ++qq){
      int idx8 = (tid + qq*256)*8;
      int r = idx8 >> 6, k = idx8 & 63;
      const float* src = Wv + (size_t)(n0+r)*3072 + k0 + k;
      float4 v0 = *(const float4*)src;
      float4 v1 = *(const float4*)(src+4);
      u16x8 o;
      o[0]=f2bf(v0.x); o[1]=f2bf(v0.y); o[2]=f2bf(v0.z); o[3]=f2bf(v0.w);
      o[4]=f2bf(v1.x); o[5]=f2bf(v1.y); o[6]=f2bf(v1.z); o[7]=f2bf(v1.w);
      *(u16x8*)(Bt + r*72 + k) = o;
    }
    __syncthreads();
    #pragma unroll
    for (int ks = 0; ks < 2; ++ks){
      s16x8 af[4], bf[4];
      #pragma unroll
      for (int fi=0;fi<4;++fi)
        af[fi] = *(const s16x8*)(Ab + (wr*64+fi*16+(l&15))*72 + ks*32 + (l>>4)*8);
      #pragma unroll
      for (int fj=0;fj<4;++fj)
        bf[fj] = *(const s16x8*)(Bt + (wc*64+fj*16+(l&15))*72 + ks*32 + (l>>4)*8);
      #pragma unroll
      for (int fi=0;fi<4;++fi){
        #pragma unroll
        for (int fj=0;fj<4;++fj)
          acc[fi][fj] = __builtin_amdgcn_mfma_f32_16x16x32_bf16(af[fi], bf[fj], acc[fi][fj], 0,0,0);
      }
    }
    __syncthreads();
  }
  #pragma unroll
  for (int fj=0;fj<4;++fj){
    int col = n0 + wc*64 + fj*16 + (l&15);
    float bias = bv[col];
    #pragma unroll
    for (int fi=0;fi<4;++fi){
      #pragma unroll
      for (int j=0;j<4;++j){
        int row = m0 + wr*64 + fi*16 + (l>>4)*4 + j;
        out[(size_t)row*V_ + col] = acc[fi][fj][j] + bias;
      }
    }
  }
}

// ---------------- in-place log-softmax over rows of 32000 ----------------
__global__ void k_logsoftmax(float* __restrict__ out){
  int row = blockIdx.x;
  float* x = out + (size_t)row*V_;
  int tid = threadIdx.x;
  __shared__ float red[64];
  float m = -1e30f;
  for (int c = tid; c < V_; c += 256) m = fmaxf(m, x[c]);
  #pragma unroll
  for (int o=1;o<64;o<<=1) m = fmaxf(m, __shfl_xor(m,o));
  if ((tid&63)==0) red[tid>>6] = m;
  __syncthreads();
  m = fmaxf(fmaxf(red[0],red[1]), fmaxf(red[2],red[3]));
  float s = 0.f;
  for (int c = tid; c < V_; c += 256) s += expf(x[c]-m);
  #pragma unroll
  for (int o=1;o<64;o<<=1) s += __shfl_xor(s,o);
  if ((tid&63)==0) red[8 + (tid>>6)] = s;
  __syncthreads();
  s = red[8]+red[9]+red[10]+red[11];
  float lse = m + logf(s);
  for (int c = tid; c < V_; c += 256) x[c] = x[c] - lse;
}

extern "C" void kernel_launch(void* const* d_in, const int* in_sizes, int n_in,
                              void* d_out, int out_size, void* d_ws, size_t ws_size,
                              hipStream_t stream){
  (void)in_sizes; (void)n_in; (void)out_size;
  const int*   enc_in = (const int*)d_in[0];
  const int*   dec_in = (const int*)d_in[1];
  const float* h0   = (const float*)d_in[4];
  const float* c0   = (const float*)d_in[5];
  const float* emb  = (const float*)d_in[6];
  const float* Wih_f= (const float*)d_in[7];
  const float* Whh_f= (const float*)d_in[8];
  const float* b_f  = (const float*)d_in[9];
  const float* Wih_b= (const float*)d_in[10];
  const float* Whh_b= (const float*)d_in[11];
  const float* b_b  = (const float*)d_in[12];
  const float* Wih_d= (const float*)d_in[13];
  const float* Whh_d= (const float*)d_in[14];
  const float* b_d  = (const float*)d_in[15];
  const float* W_ea = (const float*)d_in[16];
  const float* W_da = (const float*)d_in[17];
  const float* W_v  = (const float*)d_in[18];
  const float* b_v  = (const float*)d_in[19];
  float* out = (float*)d_out;
  char* ws = (char*)d_ws;

  size_t o_bars   = 0;
  size_t o_accum  = 256;
  size_t o_xs     = o_accum + 25600;
  size_t o_decemb = o_xs + (size_t)6400*256*2;
  size_t o_Wenc   = o_decemb + (size_t)1024*256*2;
  size_t o_Wd     = o_Wenc + (size_t)2*2048*768*2;
  size_t o_WeaT   = o_Wd + (size_t)4096*3328*2;
  size_t o_WdaT   = o_WeaT + (size_t)1024*1024*2;
  size_t o_enc    = o_WdaT + (size_t)1024*1024*2;
  size_t o_hbuf   = o_enc + (size_t)16*400*1024*2;
  size_t o_h0dec  = o_hbuf + (size_t)2*2*16*512*2;
  size_t o_c0dec  = o_h0dec + (size_t)16*1024*4;
  size_t o_hreg   = o_c0dec + (size_t)16*1024*4;
  size_t o_xbuf   = o_hreg + (size_t)2*16*1024*2;
  size_t o_q      = o_xbuf + (size_t)16*2304*2;
  size_t o_pctx   = o_q + (size_t)2*16*1024*4;
  size_t o_psum   = o_pctx + (size_t)128*1024*4;
  size_t o_ctxd   = o_psum + 512;
  size_t o_bufh   = o_ctxd + (size_t)16*1024*4;
  size_t o_Av     = o_bufh + (size_t)64*16*1024*4;

  unsigned* bars        = (unsigned*)(ws + o_bars);
  float* accum          = (float*)(ws + o_accum);
  unsigned short* xs    = (unsigned short*)(ws + o_xs);
  unsigned short* decemb= (unsigned short*)(ws + o_decemb);
  unsigned short* Wenc  = (unsigned short*)(ws + o_Wenc);
  unsigned short* Wd    = (unsigned short*)(ws + o_Wd);
  unsigned short* WeaT  = (unsigned short*)(ws + o_WeaT);
  unsigned short* WdaT  = (unsigned short*)(ws + o_WdaT);
  unsigned short* encO  = (unsigned short*)(ws + o_enc);
  unsigned short* hbuf  = (unsigned short*)(ws + o_hbuf);
  float* h0dec          = (float*)(ws + o_h0dec);
  float* c0dec          = (float*)(ws + o_c0dec);
  unsigned short* hreg  = (unsigned short*)(ws + o_hreg);
  unsigned short* xbuf  = (unsigned short*)(ws + o_xbuf);
  float* q              = (float*)(ws + o_q);
  float* pctx           = (float*)(ws + o_pctx);
  float* psum           = (float*)(ws + o_psum);
  float* ctxd           = (float*)(ws + o_ctxd);
  float* bufh           = (float*)(ws + o_bufh);
  unsigned short* Av    = (unsigned short*)(ws + o_Av);

  hipFuncSetAttribute((const void*)k_encoder, hipFuncAttributeMaxDynamicSharedMemorySize, 131072);
  hipFuncSetAttribute((const void*)k_decoder, hipFuncAttributeMaxDynamicSharedMemorySize, 131072);

  k_init<<<26, 256, 0, stream>>>(bars, accum);
  k_gather<<<1600, 256, 0, stream>>>(emb, enc_in, xs, TE_);
  k_gather<<<256, 256, 0, stream>>>(emb, dec_in, decemb, TD_);
  k_prep_enc<<<1536, 256, 0, stream>>>(Wih_f, Whh_f, Wih_b, Whh_b, Wenc);
  k_prep_dec<<<6656, 256, 0, stream>>>(Wih_d, Whh_d, Wd);
  dim3 tg(32, 32, 2);
  k_transpose_bf<<<tg, 256, 0, stream>>>(W_ea, W_da, WeaT, WdaT);
  k_encoder<<<64, 256, 128512, stream>>>(xs, Wenc, b_f, b_b, h0, c0, encO, hbuf, h0dec, c0dec, bars);
  k_dec_init<<<64, 256, 0, stream>>>(h0dec, hreg);
  k_decoder<<<192, 256, 127488, stream>>>(decemb, Wd, b_d, WeaT, WdaT, encO, c0dec,
                                          hreg, xbuf, q, accum, pctx, psum, ctxd, bufh, Av,
                                          out + (size_t)32768000, bars);
  k_vocab_gemm<<<2048, 256, 0, stream>>>(Av, W_v, b_v, out);
  k_logsoftmax<<<1024, 256, 0, stream>>>(out);
}

// Round 2
// 6192.085 us; speedup vs baseline: 1.8389x; 1.8389x over previous
//
#include <hip/hip_runtime.h>
#include <math.h>

#define B_  16
#define TE_ 400
#define TD_ 64
#define E_  256
#define H_  512
#define H2_ 1024
#define V_  32000
#define KE_ 768

typedef __attribute__((ext_vector_type(4))) float f32x4;
typedef __attribute__((ext_vector_type(8))) short s16x8;
typedef __attribute__((ext_vector_type(8))) unsigned short u16x8;
typedef __attribute__((ext_vector_type(4))) unsigned short u16x4;

__device__ __forceinline__ float bf2f(unsigned short u){
  union { unsigned int i; float f; } v; v.i = ((unsigned int)u) << 16; return v.f;
}
__device__ __forceinline__ unsigned short f2bf(float f){
  union { float f; unsigned int i; } v; v.f = f;
  return (unsigned short)((v.i + 0x7fffu + ((v.i >> 16) & 1u)) >> 16);
}
__device__ __forceinline__ float sigmoidf_(float x){ return 1.f/(1.f + expf(-x)); }

__device__ __forceinline__ void gl_lds16(const void* gsrc, void* ldst){
  __builtin_amdgcn_global_load_lds(
      (const __attribute__((address_space(1))) unsigned int*)gsrc,
      (__attribute__((address_space(3))) unsigned int*)ldst, 16, 0, 0);
}

// fast monotonic barrier: 8-way split arrivals (fire-and-forget), leader polls,
// gen broadcast. obj = 512 u32 (2KB): counters at [k*32], gen at [256].
__device__ __forceinline__ void fast_bar(unsigned* obj, unsigned nwg, unsigned widx, unsigned epoch){
  __syncthreads();
  if (threadIdx.x == 0){
    __threadfence();
    __hip_atomic_fetch_add(&obj[(widx & 7u)*32], 1u, __ATOMIC_RELAXED, __HIP_MEMORY_SCOPE_AGENT);
    if (widx == 0){
      for(;;){
        unsigned s = 0;
        #pragma unroll
        for (int k2 = 0; k2 < 8; ++k2)
          s += __hip_atomic_load(&obj[k2*32], __ATOMIC_RELAXED, __HIP_MEMORY_SCOPE_AGENT);
        if (s >= nwg*epoch) break;
      }
      __hip_atomic_store(&obj[256], epoch, __ATOMIC_RELEASE, __HIP_MEMORY_SCOPE_AGENT);
    } else {
      while (__hip_atomic_load(&obj[256], __ATOMIC_RELAXED, __HIP_MEMORY_SCOPE_AGENT) < epoch)
        __builtin_amdgcn_s_sleep(1);
    }
    __threadfence();
  }
  __syncthreads();
}

// ---------------- init ----------------
__global__ void k_init(unsigned* bars, float* accum){
  int gid = blockIdx.x*256 + threadIdx.x;
  if (gid < 4096) bars[gid] = 0u;
  if (gid < B_*TE_) accum[gid] = 0.f;
}

// ---------------- embedding gather (f32 -> bf16), out[(t*16+b)][e] ----------------
__global__ void k_gather(const float* __restrict__ emb, const int* __restrict__ idx,
                         unsigned short* __restrict__ out, int T){
  int wv = threadIdx.x >> 6, l = threadIdx.x & 63;
  int row = blockIdx.x*4 + wv;
  if (row >= T*B_) return;
  int t = row >> 4, b = row & 15;
  int tok = idx[b*T + t];
  float4 v = *(const float4*)(emb + (size_t)tok*E_ + l*4);
  u16x4 o; o[0]=f2bf(v.x); o[1]=f2bf(v.y); o[2]=f2bf(v.z); o[3]=f2bf(v.w);
  *(u16x4*)(out + (size_t)row*E_ + l*4) = o;
}

// ---------------- transpose+convert W_da -> [j][d] bf16 ----------------
__global__ void k_transpose_bf(const float* __restrict__ s, unsigned short* __restrict__ d){
  __shared__ float tile[32][33];
  int tx = threadIdx.x & 31, ty = threadIdx.x >> 5;
  int d0 = blockIdx.x*32, j0 = blockIdx.y*32;
  for (int yy = 0; yy < 32; yy += 8)
    tile[ty+yy][tx] = s[(size_t)(d0+ty+yy)*H2_ + j0 + tx];
  __syncthreads();
  for (int yy = 0; yy < 32; yy += 8)
    d[(size_t)(j0+ty+yy)*H2_ + d0 + tx] = f2bf(tile[tx][ty+yy]);
}

// ---------------- prep encoder weights: gate-grouped [dir][2048][768] bf16 ----------------
__global__ void k_prep_enc(const float* __restrict__ Wih_f, const float* __restrict__ Whh_f,
                           const float* __restrict__ Wih_b, const float* __restrict__ Whh_b,
                           unsigned short* __restrict__ Wenc){
  int it = blockIdx.x*256 + threadIdx.x;
  int dir = it / (2048*96); int rem = it % (2048*96);
  int pr = rem / 96; int kc = rem % 96; int k0 = kc*8;
  int g = pr >> 6, r = pr & 63, gate = r >> 4, ul = r & 15;
  int orig = gate*H_ + g*16 + ul;
  const float* Wih = dir ? Wih_b : Wih_f;
  const float* Whh = dir ? Whh_b : Whh_f;
  u16x8 o;
  #pragma unroll
  for (int e = 0; e < 8; ++e){
    int k = k0 + e;
    float v = (k < E_) ? Wih[(size_t)orig*E_ + k] : Whh[(size_t)orig*H_ + (k - E_)];
    o[e] = f2bf(v);
  }
  *(u16x8*)(Wenc + ((size_t)dir*2048 + pr)*KE_ + k0) = o;
}

// ---------------- prep decoder weights: gate-grouped + XOR-swizzled blocks ----------------
__global__ void k_prep_dec(const float* __restrict__ Wih_d, const float* __restrict__ Whh_d,
                           unsigned short* __restrict__ Wd){
  int it = blockIdx.x*256 + threadIdx.x;       // total 64*26*64*16
  int g = it / (26*64*16); int rem = it % (26*64*16);
  int kblk = rem / (64*16); int rem2 = rem % (64*16);
  int row = rem2 >> 4; int k8 = rem2 & 15;
  int gate = row >> 4, ul = row & 15;
  int orig = gate*H2_ + g*16 + ul;
  int kbase = kblk*128 + k8*8;
  u16x8 o;
  #pragma unroll
  for (int e = 0; e < 8; ++e){
    int k = kbase + e;
    float v = (k < 2304) ? Wih_d[(size_t)orig*2304 + k] : Whh_d[(size_t)orig*H2_ + (k-2304)];
    o[e] = f2bf(v);
  }
  size_t byteoff = (size_t)g*425984 + (size_t)kblk*16384 + (size_t)(row*256 + ((k8*16) ^ ((row&7)<<4)));
  *(u16x8*)((char*)Wd + byteoff) = o;
}

// ---------------- persistent bi-LSTM encoder (per-direction fast barrier) ----------------
__global__ void __launch_bounds__(256, 1) k_encoder(
    const unsigned short* __restrict__ xs,
    const unsigned short* __restrict__ Wenc,
    const float* __restrict__ b_f, const float* __restrict__ b_b,
    const float* __restrict__ h0, const float* __restrict__ c0,
    unsigned short* __restrict__ enc_out,
    unsigned short* __restrict__ hbuf,
    float* __restrict__ h0dec, float* __restrict__ c0dec,
    unsigned* __restrict__ bars)
{
  extern __shared__ char smem[];
  unsigned short* Wt = (unsigned short*)smem;            // [64][776]
  unsigned short* At = Wt + 64*776;                      // [16][776]
  float* zl = (float*)(At + 16*776);                     // [4][16][16]
  int tid = threadIdx.x;
  int w = blockIdx.x;
  int dir = w >> 5, g = w & 31;
  int wv = tid >> 6, l = tid & 63;
  unsigned* bobj = bars + dir*512;
  {
    const unsigned short* Wsrc = Wenc + ((size_t)dir*2048 + g*64)*KE_;
    int r = tid >> 2, s = tid & 3;
    for (int c = 0; c < 24; ++c)
      *(u16x8*)(Wt + r*776 + s*192 + c*8) = *(const u16x8*)(Wsrc + (size_t)r*KE_ + s*192 + c*8);
  }
  const float* bias = dir ? b_b : b_f;
  int bb = tid >> 4, ul = tid & 15;
  float creg = c0[((size_t)dir*16 + bb)*H_ + g*16 + ul];
  int kchunk = (l >> 4) * 8;
  float bia = bias[wv*H_ + g*16 + (l&15)];
  f32x4 bias4 = { bia, bia, bia, bia };
  f32x4 zero4 = { 0.f, 0.f, 0.f, 0.f };
  __syncthreads();
  for (int t = 0; t < TE_; ++t){
    int tg = dir ? (TE_-1 - t) : t;
    {
      int r = tid >> 4, s = tid & 15;
      *(u16x8*)(At + r*776 + s*16)     = *(const u16x8*)(xs + ((size_t)tg*16 + r)*E_ + s*16);
      *(u16x8*)(At + r*776 + s*16 + 8) = *(const u16x8*)(xs + ((size_t)tg*16 + r)*E_ + s*16 + 8);
      if (t == 0){
        for (int e = 0; e < 32; ++e)
          At[r*776 + 256 + s*32 + e] = f2bf(h0[((size_t)dir*16 + r)*H_ + s*32 + e]);
      } else {
        const unsigned short* hsrc = hbuf + ((size_t)dir*2 + (t&1))*(16*H_) + r*H_ + s*32;
        for (int c = 0; c < 4; ++c)
          *(u16x8*)(At + r*776 + 256 + s*32 + c*8) = *(const u16x8*)(hsrc + c*8);
      }
    }
    __syncthreads();
    f32x4 acc0 = bias4, acc1 = zero4;
    const unsigned short* brow = Wt + (wv*16 + (l&15))*776 + kchunk;
    const unsigned short* ap   = At + (l&15)*776 + kchunk;
    #pragma unroll
    for (int ks = 0; ks < 24; ++ks){
      s16x8 afr = *(const s16x8*)(ap + ks*32);
      s16x8 bfr = *(const s16x8*)(brow + ks*32);
      if (ks & 1) acc1 = __builtin_amdgcn_mfma_f32_16x16x32_bf16(afr, bfr, acc1, 0, 0, 0);
      else        acc0 = __builtin_amdgcn_mfma_f32_16x16x32_bf16(afr, bfr, acc0, 0, 0, 0);
    }
    f32x4 acc = acc0 + acc1;
    #pragma unroll
    for (int j = 0; j < 4; ++j)
      zl[wv*256 + ((l>>4)*4 + j)*16 + (l&15)] = acc[j];
    __syncthreads();
    float zi = zl[0*256 + bb*16 + ul];
    float zf = zl[1*256 + bb*16 + ul];
    float zg = zl[2*256 + bb*16 + ul];
    float zo = zl[3*256 + bb*16 + ul];
    float iv = sigmoidf_(zi), fv = sigmoidf_(zf), gv = tanhf(zg), ov = sigmoidf_(zo);
    float cc = fv*creg + iv*gv;
    float hh = ov * tanhf(cc);
    creg = cc;
    int u = g*16 + ul;
    unsigned short hb = f2bf(hh);
    hbuf[((size_t)dir*2 + ((t+1)&1))*(16*H_) + bb*H_ + u] = hb;
    enc_out[((size_t)bb*TE_ + tg)*H2_ + dir*H_ + u] = hb;
    if (t == TE_-1){
      h0dec[(size_t)bb*H2_ + dir*H_ + u] = hh;
      c0dec[(size_t)bb*H2_ + dir*H_ + u] = cc;
    }
    fast_bar(bobj, 32, (unsigned)g, (unsigned)(t+1));
  }
}

__global__ void k_dec_init(const float* __restrict__ h0dec, unsigned short* __restrict__ hreg){
  int gid = blockIdx.x*256 + threadIdx.x;
  if (gid < 16384) hreg[gid] = f2bf(h0dec[gid]);
}

// ---------------- Penc = enc_out @ W_ea^T  (bf16 out) ----------------
__global__ void __launch_bounds__(256, 2) k_penc(
    const unsigned short* __restrict__ enc,  // [6400][1024]
    const float* __restrict__ Wea,           // [1024][1024]
    unsigned short* __restrict__ P)          // [6400][1024]
{
  __shared__ unsigned short Ab[128*72];
  __shared__ unsigned short Bt[128*72];
  int p = blockIdx.x;
  int mt = p >> 3, nt = p & 7;
  int m0 = mt*128, n0 = nt*128;
  int tid = threadIdx.x, wvv = tid>>6, l = tid&63;
  int wr = wvv>>1, wc = wvv&1;
  f32x4 zero4 = {0.f,0.f,0.f,0.f};
  f32x4 acc[4][4];
  #pragma unroll
  for (int a=0;a<4;++a){
    #pragma unroll
    for (int b=0;b<4;++b) acc[a][b] = zero4;
  }
  for (int k0 = 0; k0 < 1024; k0 += 64){
    #pragma unroll
    for (int qq = 0; qq < 4; ++qq){
      int idx8 = (tid + qq*256)*8;
      int r = idx8 >> 6, k = idx8 & 63;
      *(u16x8*)(Ab + r*72 + k) = *(const u16x8*)(enc + (size_t)(m0+r)*1024 + k0 + k);
    }
    #pragma unroll
    for (int qq = 0; qq < 4; ++qq){
      int idx8 = (tid + qq*256)*8;
      int r = idx8 >> 6, k = idx8 & 63;
      const float* src = Wea + (size_t)(n0+r)*1024 + k0 + k;
      float4 v0 = *(const float4*)src;
      float4 v1 = *(const float4*)(src+4);
      u16x8 o;
      o[0]=f2bf(v0.x); o[1]=f2bf(v0.y); o[2]=f2bf(v0.z); o[3]=f2bf(v0.w);
      o[4]=f2bf(v1.x); o[5]=f2bf(v1.y); o[6]=f2bf(v1.z); o[7]=f2bf(v1.w);
      *(u16x8*)(Bt + r*72 + k) = o;
    }
    __syncthreads();
    #pragma unroll
    for (int ks = 0; ks < 2; ++ks){
      s16x8 af[4], bf[4];
      #pragma unroll
      for (int fi=0;fi<4;++fi)
        af[fi] = *(const s16x8*)(Ab + (wr*64+fi*16+(l&15))*72 + ks*32 + (l>>4)*8);
      #pragma unroll
      for (int fj=0;fj<4;++fj)
        bf[fj] = *(const s16x8*)(Bt + (wc*64+fj*16+(l&15))*72 + ks*32 + (l>>4)*8);
      #pragma unroll
      for (int fi=0;fi<4;++fi){
        #pragma unroll
        for (int fj=0;fj<4;++fj)
          acc[fi][fj] = __builtin_amdgcn_mfma_f32_16x16x32_bf16(af[fi], bf[fj], acc[fi][fj], 0,0,0);
      }
    }
    __syncthreads();
  }
  #pragma unroll
  for (int fj=0;fj<4;++fj){
    int col = n0 + wc*64 + fj*16 + (l&15);
    #pragma unroll
    for (int fi=0;fi<4;++fi){
      #pragma unroll
      for (int j=0;j<4;++j){
        int row = m0 + wr*64 + fi*16 + (l>>4)*4 + j;
        P[(size_t)row*1024 + col] = f2bf(acc[fi][fj][j]);
      }
    }
  }
}

__device__ __forceinline__ void s4_issue(const char* gblk, char* Bb, int wv, int l, int kblk, int buf){
  const char* gsrc = gblk + (size_t)kblk*16384 + wv*4096 + (size_t)l*16;
  char* lb = Bb + buf*16384 + wv*4096;
  #pragma unroll
  for (int qq = 0; qq < 4; ++qq)
    gl_lds16(gsrc + qq*1024, lb + qq*1024);
}

// ---------------- persistent attention decoder (3 barriers/step) ----------------
__global__ void __launch_bounds__(256, 1) k_decoder(
  const unsigned short* __restrict__ dec_emb,  // [1024][256]
  const unsigned short* __restrict__ Wd,
  const float* __restrict__ b_d,
  const unsigned short* __restrict__ WdaT,     // [j][d] bf16
  const unsigned short* __restrict__ enc_out,  // [16][400][1024]
  const unsigned short* __restrict__ Penc,     // [16][400][1024]
  const float* __restrict__ c0dec,
  unsigned short* __restrict__ hreg,    // [2][16][1024] bf16
  unsigned short* __restrict__ xbuf,    // [16][2048] bf16 (ctx_e | ctx_d)
  float* __restrict__ q,                // [16][1024] f32 (q_d)
  float* __restrict__ accum,            // [16][400]
  float* __restrict__ pctx,             // [128][1024]
  float* __restrict__ psum,             // [128]
  float* __restrict__ bufh,             // [64][16][1024] f32
  unsigned short* __restrict__ Av,      // [1024][3072]
  float* __restrict__ outHC,            // [2][16][1024]
  unsigned* __restrict__ bars)
{
  extern __shared__ char smem[];
  int tid = threadIdx.x, w = blockIdx.x;
  int wv = tid >> 6, l = tid & 63;
  unsigned* objA = bars + 1024;
  unsigned* objB = bars + 1536;
  unsigned* objC = bars + 2048;

  // role LDS views
  unsigned short* At = (unsigned short*)smem;            // [16][3336] (w<64, P_C)
  char*  Bb = smem + 106752;                             // 3 x 16KB   (w<64, P_C)
  float* zl = (float*)(smem + 155904);                   // [4][16][16]
  unsigned short* Ah = (unsigned short*)smem;            // [16][1032] (w<64, P_A)
  unsigned short* Wq = Ah + 16*1032;
  float* zq = (float*)(Wq + 16*1032);
  float* dscL = (float*)(smem + 155904);                 // [64] (w<16, P_B)
  unsigned short* encL = (unsigned short*)smem;          // [50][1024] (w>=64)
  float* epL = (float*)(smem + 102400);                  // [50]

  int eb = 0, ec = 0;
  if (w >= 64){ eb = (w-64) >> 3; ec = (w-64) & 7; }
  bool isL = (w < 64);

  if (w >= 64){
    for (int rr = 0; rr < 50; ++rr){
      const unsigned short* src = enc_out + ((size_t)eb*TE_ + ec*50 + rr)*H2_;
      *(u16x4*)(encL + rr*1024 + tid*4) = *(const u16x4*)(src + tid*4);
    }
    __syncthreads();
  }
  float creg = 0.f;
  int bb = tid >> 4, ul = tid & 15;

  for (int i = 0; i < TD_; ++i){
    // ======== P_A: q_d (w<64) || enc-attention (w>=64) ========
    if (isL){
      int r = tid >> 4, s = tid & 15;
      const unsigned short* hsrc = hreg + (i&1)*16384 + r*H2_ + s*64;
      for (int c = 0; c < 8; ++c)
        *(u16x8*)(Ah + r*1032 + s*64 + c*8) = *(const u16x8*)(hsrc + c*8);
      __syncthreads();
      const unsigned short* Wsrc = WdaT + (size_t)w*16*H2_;
      for (int c = 0; c < 8; ++c)
        *(u16x8*)(Wq + r*1032 + s*64 + c*8) = *(const u16x8*)(Wsrc + (size_t)r*H2_ + s*64 + c*8);
      __syncthreads();
      f32x4 acc = {0.f,0.f,0.f,0.f};
      const unsigned short* ap = Ah + (l&15)*1032 + wv*256 + (l>>4)*8;
      const unsigned short* bp = Wq + (l&15)*1032 + wv*256 + (l>>4)*8;
      #pragma unroll
      for (int ks = 0; ks < 8; ++ks){
        s16x8 afr = *(const s16x8*)(ap + ks*32);
        s16x8 bfr = *(const s16x8*)(bp + ks*32);
        acc = __builtin_amdgcn_mfma_f32_16x16x32_bf16(afr, bfr, acc, 0,0,0);
      }
      #pragma unroll
      for (int j = 0; j < 4; ++j)
        zq[wv*256 + (l&15)*16 + (l>>4)*4 + j] = acc[j];
      __syncthreads();
      float qv = zq[0*256 + (tid&15)*16 + (tid>>4)] + zq[1*256 + (tid&15)*16 + (tid>>4)]
               + zq[2*256 + (tid&15)*16 + (tid>>4)] + zq[3*256 + (tid&15)*16 + (tid>>4)];
      q[(size_t)(tid>>4)*H2_ + w*16 + (tid&15)] = qv;
    } else {
      // enc-attention: scores via Penc (h in registers), partial ctx
      const unsigned short* hb_ = hreg + (i&1)*16384 + eb*H2_ + l*16;
      u16x8 hv0 = *(const u16x8*)hb_;
      u16x8 hv1 = *(const u16x8*)(hb_ + 8);
      float hf[16];
      #pragma unroll
      for (int c = 0; c < 8; ++c){ hf[c] = bf2f(hv0[c]); hf[8+c] = bf2f(hv1[c]); }
      for (int rr = wv; rr < 50; rr += 4){
        const unsigned short* pr = Penc + ((size_t)(eb*TE_ + ec*50 + rr))*H2_ + l*16;
        u16x8 p0 = *(const u16x8*)pr;
        u16x8 p1 = *(const u16x8*)(pr + 8);
        float sc = 0.f;
        #pragma unroll
        for (int c = 0; c < 8; ++c) sc += hf[c]*bf2f(p0[c]);
        #pragma unroll
        for (int c = 0; c < 8; ++c) sc += hf[8+c]*bf2f(p1[c]);
        #pragma unroll
        for (int o = 1; o < 64; o <<= 1) sc += __shfl_xor(sc, o);
        if (l == 0){
          int t = ec*50 + rr;
          float es = expf(sc);
          float aold = accum[eb*TE_ + t];
          float denom = (i == 0) ? 1.f : aold;
          accum[eb*TE_ + t] = aold + es;
          epL[rr] = es / denom;
        }
      }
      __syncthreads();
      float tot = 0.f;
      for (int rr = 0; rr < 50; ++rr) tot += epL[rr];
      float a0=0.f,a1=0.f,a2=0.f,a3=0.f;
      for (int rr = 0; rr < 50; ++rr){
        float wgt = epL[rr];
        u16x4 ev = *(const u16x4*)(encL + rr*1024 + tid*4);
        a0 += wgt*bf2f(ev[0]); a1 += wgt*bf2f(ev[1]); a2 += wgt*bf2f(ev[2]); a3 += wgt*bf2f(ev[3]);
      }
      int slot = w - 64;
      float4 o4; o4.x=a0; o4.y=a1; o4.z=a2; o4.w=a3;
      *(float4*)(pctx + (size_t)slot*1024 + tid*4) = o4;
      if (tid == 0) psum[slot] = tot;
      __syncthreads();   // epL stable until next overwrite (after 3 barriers)
    }
    fast_bar(objA, 192, (unsigned)w, (unsigned)(i+1));

    // ======== P_B: dec-attention (w<16) || pctx reduce (w16..31) ========
    if (w < 16){
      int b = w;
      if (i == 0){
        int col = tid*4;
        u16x4 z4 = {0,0,0,0};
        *(u16x4*)(xbuf + (size_t)b*2048 + 1024 + col) = z4;
        *(u16x4*)(Av + ((size_t)b*TD_ + i)*3072 + 2048 + col) = z4;
      } else {
        const float* qsrc = q + (size_t)b*H2_ + l*16;
        float4 q0 = *(const float4*)(qsrc);
        float4 q1 = *(const float4*)(qsrc+4);
        float4 q2 = *(const float4*)(qsrc+8);
        float4 q3 = *(const float4*)(qsrc+12);
        for (int tp = wv; tp < i; tp += 4){
          const float* br = bufh + ((size_t)tp*16 + b)*H2_ + l*16;
          float4 b0 = *(const float4*)(br);
          float4 b1 = *(const float4*)(br+4);
          float4 b2 = *(const float4*)(br+8);
          float4 b3 = *(const float4*)(br+12);
          float sc = q0.x*b0.x + q0.y*b0.y + q0.z*b0.z + q0.w*b0.w
                   + q1.x*b1.x + q1.y*b1.y + q1.z*b1.z + q1.w*b1.w
                   + q2.x*b2.x + q2.y*b2.y + q2.z*b2.z + q2.w*b2.w
                   + q3.x*b3.x + q3.y*b3.y + q3.z*b3.z + q3.w*b3.w;
          #pragma unroll
          for (int o = 1; o < 64; o <<= 1) sc += __shfl_xor(sc, o);
          if (l == 0) dscL[tp] = sc;
        }
        __syncthreads();
        float scv = (l < i) ? dscL[l] : -1e30f;
        float m = scv;
        #pragma unroll
        for (int o = 1; o < 64; o <<= 1) m = fmaxf(m, __shfl_xor(m, o));
        float e = (l < i) ? expf(scv - m) : 0.f;
        float ssum = e;
        #pragma unroll
        for (int o = 1; o < 64; o <<= 1) ssum += __shfl_xor(ssum, o);
        float wgt = e / ssum;
        int col = wv*256 + l*4;
        float c0_=0.f,c1_=0.f,c2_=0.f,c3_=0.f;
        for (int tp = 0; tp < i; ++tp){
          float wt = __shfl(wgt, tp);
          const float* br = bufh + ((size_t)tp*16 + b)*H2_ + col;
          float4 bv = *(const float4*)br;
          c0_ += wt*bv.x; c1_ += wt*bv.y; c2_ += wt*bv.z; c3_ += wt*bv.w;
        }
        u16x4 o4; o4[0]=f2bf(c0_); o4[1]=f2bf(c1_); o4[2]=f2bf(c2_); o4[3]=f2bf(c3_);
        *(u16x4*)(xbuf + (size_t)b*2048 + 1024 + col) = o4;
        *(u16x4*)(Av + ((size_t)b*TD_ + i)*3072 + 2048 + col) = o4;
      }
    } else if (w < 32){
      int b = w - 16;
      float sx=0.f, sy=0.f, sz=0.f, sw=0.f, pst=0.f;
      for (int c = 0; c < 8; ++c){
        float4 v = *(const float4*)(pctx + (size_t)(b*8+c)*1024 + tid*4);
        sx += v.x; sy += v.y; sz += v.z; sw += v.w;
        pst += psum[b*8+c];
      }
      float inv = 1.f/pst;
      u16x4 o; o[0]=f2bf(sx*inv); o[1]=f2bf(sy*inv); o[2]=f2bf(sz*inv); o[3]=f2bf(sw*inv);
      *(u16x4*)(xbuf + (size_t)b*2048 + tid*4) = o;
      *(u16x4*)(Av + ((size_t)b*TD_ + i)*3072 + 1024 + tid*4) = o;
    }
    fast_bar(objB, 192, (unsigned)w, (unsigned)(i+1));

    // ======== P_C: decoder LSTM matvec (w<64), pipelined weight stream ========
    if (isL){
      int r = tid >> 4, s = tid & 15;
      // At: [emb 0..255 | ctx 256..2303 | h 2304..3327]
      *(u16x8*)(At + r*3336 + s*16)     = *(const u16x8*)(dec_emb + ((size_t)i*16 + r)*E_ + s*16);
      *(u16x8*)(At + r*3336 + s*16 + 8) = *(const u16x8*)(dec_emb + ((size_t)i*16 + r)*E_ + s*16 + 8);
      for (int c = 0; c < 16; ++c)
        *(u16x8*)(At + r*3336 + 256 + s*128 + c*8) = *(const u16x8*)(xbuf + (size_t)r*2048 + s*128 + c*8);
      for (int c = 0; c < 8; ++c)
        *(u16x8*)(At + r*3336 + 2304 + s*64 + c*8) = *(const u16x8*)(hreg + (i&1)*16384 + (size_t)r*H2_ + s*64 + c*8);
      __syncthreads();
      float bia = b_d[wv*H2_ + w*16 + (l&15)];
      f32x4 acc0 = { bia, bia, bia, bia };
      f32x4 acc1 = { 0.f, 0.f, 0.f, 0.f };
      const char* gblk = (const char*)Wd + (size_t)w*425984;
      int r2 = wv*16 + (l&15);
      s4_issue(gblk, Bb, wv, l, 0, 0);
      s4_issue(gblk, Bb, wv, l, 1, 1);
      for (int kblk = 0; kblk < 26; ++kblk){
        int buf = kblk % 3;
        if (kblk + 2 < 26) s4_issue(gblk, Bb, wv, l, kblk+2, (kblk+2)%3);
        if (kblk < 24)       asm volatile("s_waitcnt vmcnt(8)" ::: "memory");
        else if (kblk == 24) asm volatile("s_waitcnt vmcnt(4)" ::: "memory");
        else                 asm volatile("s_waitcnt vmcnt(0)" ::: "memory");
        const unsigned short* ap = At + (l&15)*3336 + kblk*128 + (l>>4)*8;
        const char* Bbase = Bb + buf*16384;
        #pragma unroll
        for (int ks = 0; ks < 4; ++ks){
          int k8 = ks*4 + (l>>4);
          int bby = r2*256 + ((k8*16) ^ ((r2&7)<<4));
          s16x8 afr = *(const s16x8*)(ap + ks*32);
          s16x8 bfr = *(const s16x8*)(Bbase + bby);
          if (ks & 1) acc1 = __builtin_amdgcn_mfma_f32_16x16x32_bf16(afr, bfr, acc1, 0,0,0);
          else        acc0 = __builtin_amdgcn_mfma_f32_16x16x32_bf16(afr, bfr, acc0, 0,0,0);
        }
      }
      f32x4 acc = acc0 + acc1;
      #pragma unroll
      for (int j = 0; j < 4; ++j)
        zl[wv*256 + ((l>>4)*4+j)*16 + (l&15)] = acc[j];
      __syncthreads();
      float zi = zl[0*256 + bb*16 + ul];
      float zf = zl[1*256 + bb*16 + ul];
      float zg = zl[2*256 + bb*16 + ul];
      float zo = zl[3*256 + bb*16 + ul];
      if (i == 0) creg = c0dec[(size_t)bb*H2_ + w*16 + ul];
      float iv = sigmoidf_(zi), fv = sigmoidf_(zf), gv = tanhf(zg), ov = sigmoidf_(zo);
      float cc = fv*creg + iv*gv;
      float hh = ov*tanhf(cc);
      creg = cc;
      int u = w*16 + ul;
      hreg[((i+1)&1)*16384 + (size_t)bb*H2_ + u] = f2bf(hh);
      Av[((size_t)bb*TD_ + i)*3072 + u] = f2bf(hh);
      bufh[((size_t)i*16 + bb)*H2_ + u] = hh;
      if (i == TD_-1){
        outHC[(size_t)bb*H2_ + u] = hh;
        outHC[16384 + (size_t)bb*H2_ + u] = cc;
      }
    }
    fast_bar(objC, 192, (unsigned)w, (unsigned)(i+1));
  }
}

// ---------------- vocab GEMM ----------------
__global__ void __launch_bounds__(256, 2) k_vocab_gemm(
    const unsigned short* __restrict__ Av,
    const float* __restrict__ Wv,
    const float* __restrict__ bv,
    float* __restrict__ out)
{
  __shared__ unsigned short Ab[128*72];
  __shared__ unsigned short Bt[128*72];
  int p = blockIdx.x;
  int mt = (p>>3)&7, nt = (p&7) + 8*(p>>6);
  if (nt >= 250) return;
  int m0 = mt*128, n0 = nt*128;
  int tid = threadIdx.x, wvv = tid>>6, l = tid&63;
  int wr = wvv>>1, wc = wvv&1;
  f32x4 zero4 = {0.f,0.f,0.f,0.f};
  f32x4 acc[4][4];
  #pragma unroll
  for (int a=0;a<4;++a){
    #pragma unroll
    for (int b=0;b<4;++b) acc[a][b] = zero4;
  }
  for (int k0 = 0; k0 < 3072; k0 += 64){
    #pragma unroll
    for (int qq = 0; qq < 4; ++qq){
      int idx8 = (tid + qq*256)*8;
      int r = idx8 >> 6, k = idx8 & 63;
      *(u16x8*)(Ab + r*72 + k) = *(const u16x8*)(Av + (size_t)(m0+r)*3072 + k0 + k);
    }
    #pragma unroll
    for (int qq = 0; qq < 4; ++qq){
      int idx8 = (tid + qq*256)*8;
      int r = idx8 >> 6, k = idx8 & 63;
      const float* src = Wv + (size_t)(n0+r)*3072 + k0 + k;
      float4 v0 = *(const float4*)src;
      float4 v1 = *(const float4*)(src+4);
      u16x8 o;
      o[0]=f2bf(v0.x); o[1]=f2bf(v0.y); o[2]=f2bf(v0.z); o[3]=f2bf(v0.w);
      o[4]=f2bf(v1.x); o[5]=f2bf(v1.y); o[6]=f2bf(v1.z); o[7]=f2bf(v1.w);
      *(u16x8*)(Bt + r*72 + k) = o;
    }
    __syncthreads();
    #pragma unroll
    for (int ks = 0; ks < 2; ++ks){
      s16x8 af[4], bf[4];
      #pragma unroll
      for (int fi=0;fi<4;++fi)
        af[fi] = *(const s16x8*)(Ab + (wr*64+fi*16+(l&15))*72 + ks*32 + (l>>4)*8);
      #pragma unroll
      for (int fj=0;fj<4;++fj)
        bf[fj] = *(const s16x8*)(Bt + (wc*64+fj*16+(l&15))*72 + ks*32 + (l>>4)*8);
      #pragma unroll
      for (int fi=0;fi<4;++fi){
        #pragma unroll
        for (int fj=0;fj<4;++fj)
          acc[fi][fj] = __builtin_amdgcn_mfma_f32_16x16x32_bf16(af[fi], bf[fj], acc[fi][fj], 0,0,0);
      }
    }
    __syncthreads();
  }
  #pragma unroll
  for (int fj=0;fj<4;++fj){
    int col = n0 + wc*64 + fj*16 + (l&15);
    float bias = bv[col];
    #pragma unroll
    for (int fi=0;fi<4;++fi){
      #pragma unroll
      for (int j=0;j<4;++j){
        int row = m0 + wr*64 + fi*16 + (l>>4)*4 + j;
        out[(size_t)row*V_ + col] = acc[fi][fj][j] + bias;
      }
    }
  }
}

// ---------------- in-place log-softmax ----------------
__global__ void k_logsoftmax(float* __restrict__ out){
  int row = blockIdx.x;
  float* x = out + (size_t)row*V_;
  int tid = threadIdx.x;
  __shared__ float red[64];
  float m = -1e30f;
  for (int c = tid; c < V_; c += 256) m = fmaxf(m, x[c]);
  #pragma unroll
  for (int o=1;o<64;o<<=1) m = fmaxf(m, __shfl_xor(m,o));
  if ((tid&63)==0) red[tid>>6] = m;
  __syncthreads();
  m = fmaxf(fmaxf(red[0],red[1]), fmaxf(red[2],red[3]));
  float s = 0.f;
  for (int c = tid; c < V_; c += 256) s += expf(x[c]-m);
  #pragma unroll
  for (int o=1;o<64;o<<=1) s += __shfl_xor(s,o);
  if ((tid&63)==0) red[8 + (tid>>6)] = s;
  __syncthreads();
  s = red[8]+red[9]+red[10]+red[11];
  float lse = m + logf(s);
  for (int c = tid; c < V_; c += 256) x[c] = x[c] - lse;
}

extern "C" void kernel_launch(void* const* d_in, const int* in_sizes, int n_in,
                              void* d_out, int out_size, void* d_ws, size_t ws_size,
                              hipStream_t stream){
  (void)in_sizes; (void)n_in; (void)out_size; (void)ws_size;
  const int*   enc_in = (const int*)d_in[0];
  const int*   dec_in = (const int*)d_in[1];
  const float* h0   = (const float*)d_in[4];
  const float* c0   = (const float*)d_in[5];
  const float* emb  = (const float*)d_in[6];
  const float* Wih_f= (const float*)d_in[7];
  const float* Whh_f= (const float*)d_in[8];
  const float* b_f  = (const float*)d_in[9];
  const float* Wih_b= (const float*)d_in[10];
  const float* Whh_b= (const float*)d_in[11];
  const float* b_b  = (const float*)d_in[12];
  const float* Wih_d= (const float*)d_in[13];
  const float* Whh_d= (const float*)d_in[14];
  const float* b_d  = (const float*)d_in[15];
  const float* W_ea = (const float*)d_in[16];
  const float* W_da = (const float*)d_in[17];
  const float* W_v  = (const float*)d_in[18];
  const float* b_v  = (const float*)d_in[19];
  float* out = (float*)d_out;
  char* ws = (char*)d_ws;

  size_t o_bars   = 0;
  size_t o_accum  = 16384;
  size_t o_q      = o_accum + 25600;
  size_t o_xs     = o_q + 65536;
  size_t o_decemb = o_xs + (size_t)6400*256*2;
  size_t o_Wenc   = o_decemb + (size_t)1024*256*2;
  size_t o_Wd     = o_Wenc + (size_t)2*2048*768*2;
  size_t o_WdaT   = o_Wd + (size_t)64*425984;
  size_t o_enc    = o_WdaT + (size_t)1024*1024*2;
  size_t o_Penc   = o_enc + (size_t)16*400*1024*2;
  size_t o_hbuf   = o_Penc + (size_t)16*400*1024*2;
  size_t o_h0dec  = o_hbuf + (size_t)2*2*16*512*2;
  size_t o_c0dec  = o_h0dec + (size_t)16*1024*4;
  size_t o_hreg   = o_c0dec + (size_t)16*1024*4;
  size_t o_xbuf   = o_hreg + (size_t)2*16*1024*2;
  size_t o_pctx   = o_xbuf + (size_t)16*2048*2;
  size_t o_psum   = o_pctx + (size_t)128*1024*4;
  size_t o_bufh   = o_psum + 512;
  size_t o_Av     = o_bufh + (size_t)64*16*1024*4;

  unsigned* bars        = (unsigned*)(ws + o_bars);
  float* accum          = (float*)(ws + o_accum);
  float* q              = (float*)(ws + o_q);
  unsigned short* xs    = (unsigned short*)(ws + o_xs);
  unsigned short* decemb= (unsigned short*)(ws + o_decemb);
  unsigned short* Wenc  = (unsigned short*)(ws + o_Wenc);
  unsigned short* Wd    = (unsigned short*)(ws + o_Wd);
  unsigned short* WdaT  = (unsigned short*)(ws + o_WdaT);
  unsigned short* encO  = (unsigned short*)(ws + o_enc);
  unsigned short* Penc  = (unsigned short*)(ws + o_Penc);
  unsigned short* hbuf  = (unsigned short*)(ws + o_hbuf);
  float* h0dec          = (float*)(ws + o_h0dec);
  float* c0dec          = (float*)(ws + o_c0dec);
  unsigned short* hreg  = (unsigned short*)(ws + o_hreg);
  unsigned short* xbuf  = (unsigned short*)(ws + o_xbuf);
  float* pctx           = (float*)(ws + o_pctx);
  float* psum           = (float*)(ws + o_psum);
  float* bufh           = (float*)(ws + o_bufh);
  unsigned short* Av    = (unsigned short*)(ws + o_Av);

  hipFuncSetAttribute((const void*)k_encoder, hipFuncAttributeMaxDynamicSharedMemorySize, 131072);
  hipFuncSetAttribute((const void*)k_decoder, hipFuncAttributeMaxDynamicSharedMemorySize, 160000);

  k_init<<<26, 256, 0, stream>>>(bars, accum);
  k_gather<<<1600, 256, 0, stream>>>(emb, enc_in, xs, TE_);
  k_gather<<<256, 256, 0, stream>>>(emb, dec_in, decemb, TD_);
  k_prep_enc<<<1536, 256, 0, stream>>>(Wih_f, Whh_f, Wih_b, Whh_b, Wenc);
  k_prep_dec<<<6656, 256, 0, stream>>>(Wih_d, Whh_d, Wd);
  dim3 tg(32, 32, 1);
  k_transpose_bf<<<tg, 256, 0, stream>>>(W_da, WdaT);
  k_encoder<<<64, 256, 128512, stream>>>(xs, Wenc, b_f, b_b, h0, c0, encO, hbuf, h0dec, c0dec, bars);
  k_penc<<<400, 256, 0, stream>>>(encO, W_ea, Penc);
  k_dec_init<<<64, 256, 0, stream>>>(h0dec, hreg);
  k_decoder<<<192, 256, 160000, stream>>>(decemb, Wd, b_d, WdaT, encO, Penc, c0dec,
                                          hreg, xbuf, q, accum, pctx, psum, bufh, Av,
                                          out + (size_t)32768000, bars);
  k_vocab_gemm<<<2048, 256, 0, stream>>>(Av, W_v, b_v, out);
  k_logsoftmax<<<1024, 256, 0, stream>>>(out);
}